// Round 5
// baseline (812.770 us; speedup 1.0000x reference)
//
#include <hip/hip_runtime.h>
#include <stdint.h>

#define BB 16
#define HH 512
#define WW 512
#define HW 262144            // 2^18
#define BHW 4194304          // 16 * 2^18
#define KSEL 262
#define CAP 8192
#define NTHREADS 256
#define BLKPB 64             // topk blocks per batch
#define CHUNK (HW / BLKPB)   // 4096 pixels per topk block
#define TOPK_BLOCKS (16 * BLKPB)

// ---------- helpers (rn intrinsics to suppress fma contraction in selection-critical math) ----------
__device__ __forceinline__ float img01(float xv) {
    return __fmul_rn(__fadd_rn(xv, 1.0f), 0.5f);
}
__device__ __forceinline__ float luma3(float c0, float c1, float c2) {
    float t = __fadd_rn(__fmul_rn(0.2989f, c0), __fmul_rn(0.587f, c1));
    return __fadd_rn(t, __fmul_rn(0.114f, c2));
}
__device__ __forceinline__ uint32_t aload(const uint32_t* p) {
    return __hip_atomic_load(p, __ATOMIC_RELAXED, __HIP_MEMORY_SCOPE_AGENT);
}
__device__ __forceinline__ unsigned long long aload64(const unsigned long long* p) {
    return __hip_atomic_load(p, __ATOMIC_RELAXED, __HIP_MEMORY_SCOPE_AGENT);
}

// ============ dark channel row pass (fused prep + topk-state init) ============
__global__ void k_dc_row(const float* __restrict__ x, float* __restrict__ Ib, float* __restrict__ rm,
                         uint32_t* __restrict__ hist4, uint32_t* __restrict__ tiecnt,
                         unsigned long long* __restrict__ gt, uint32_t* __restrict__ cnt) {
    int bid = blockIdx.x;              // 16*512
    int b = bid >> 9, y = bid & 511;
    int t = threadIdx.x;
    if (bid < 16) {
        #pragma unroll
        for (int p = 0; p < 4; ++p) hist4[p * 4096 + bid * 256 + t] = 0;
        if (bid == 0) {
            if (t < 16) { tiecnt[t] = 0; gt[t] = 0ull; }
            if (t < 8) cnt[t] = 0;
        }
    }
    __shared__ float lcm[528];         // logical [-8, 519], offset 8, pad = 1.0
    const float* xb = x + (size_t)b * 3 * HW + (size_t)y * WW;
    size_t obase = (size_t)b * HW + (size_t)y * WW;
    for (int xx = t; xx < 512; xx += 256) {
        float x0 = xb[xx], x1 = xb[HW + xx], x2 = xb[2 * HW + xx];
        float i0 = img01(x0), i1 = img01(x1), i2 = img01(x2);
        lcm[8 + xx] = fminf(i0, fminf(i1, i2));
        float tt = luma3(x0, x1, x2);
        Ib[obase + xx] = __fmul_rn(__fadd_rn(tt, 1.0f), 0.5f);
    }
    if (t < 16) lcm[(t < 8) ? t : (512 + t)] = 1.0f;
    __syncthreads();
    for (int xx = t; xx < 512; xx += 256) {
        float m = lcm[8 + xx - 7];
        #pragma unroll
        for (int k = -6; k <= 7; ++k) m = fminf(m, lcm[8 + xx + k]);
        rm[obase + xx] = m;
    }
}

// ============ second dark channel row pass (fused cmin2): x, Ap3 -> rm ============
__global__ void k_dc2_row(const float* __restrict__ x, const float* __restrict__ Ap3,
                          float* __restrict__ rm) {
    int bid = blockIdx.x;
    int b = bid >> 9, y = bid & 511;
    int t = threadIdx.x;
    __shared__ float lcm[528];
    const float* xb = x + (size_t)b * 3 * HW + (size_t)y * WW;
    float a0 = Ap3[b * 3 + 0], a1 = Ap3[b * 3 + 1], a2 = Ap3[b * 3 + 2];
    size_t obase = (size_t)b * HW + (size_t)y * WW;
    for (int xx = t; xx < 512; xx += 256) {
        float v0 = __fdiv_rn(img01(xb[xx]), a0);
        float v1 = __fdiv_rn(img01(xb[HW + xx]), a1);
        float v2 = __fdiv_rn(img01(xb[2 * HW + xx]), a2);
        lcm[8 + xx] = fminf(v0, fminf(v1, v2));
    }
    if (t < 16) lcm[(t < 8) ? t : (512 + t)] = 1.0f;
    __syncthreads();
    for (int xx = t; xx < 512; xx += 256) {
        float m = lcm[8 + xx - 7];
        #pragma unroll
        for (int k = -6; k <= 7; ++k) m = fminf(m, lcm[8 + xx + k]);
        rm[obase + xx] = m;
    }
}

// ============ col min pass (dark channel only): rm -> dc ============
__global__ void k_dc_col0(const float* __restrict__ in, float* __restrict__ out) {
    // grid 16*4*8; tile 128 cols x (64+14) rows
    int bid = blockIdx.x;
    int b = bid >> 5, cg = (bid >> 3) & 3, seg = bid & 7;
    int c0 = cg * 128, y0 = seg * 64;
    int t = threadIdx.x;
    __shared__ float tile[78 * 128];
    const float* ib = in + (size_t)b * HW;
    for (int i = t; i < 78 * 128; i += 256) {
        int rr = i >> 7, cc = i & 127;
        int gy = y0 - 7 + rr;
        tile[i] = (gy >= 0 && gy < 512) ? ib[(size_t)gy * WW + c0 + cc] : 1.0f;
    }
    __syncthreads();
    int col = t & 127;
    int rbase = (t >> 7) * 32;
    size_t obase = (size_t)b * HW + c0 + col;
    for (int rr = rbase; rr < rbase + 32; ++rr) {
        float m = tile[rr * 128 + col];
        #pragma unroll
        for (int k = 1; k < 15; ++k) m = fminf(m, tile[(rr + k) * 128 + col]);
        out[obase + (size_t)(y0 + rr) * WW] = m;
    }
}

// ============ single-kernel exact top-k + atmospheric light (cooperative) ============
// 4x8-bit radix select into 4 separate pre-zeroed histograms (no clears), grid barriers
// via device-scope arrival counters, then collect + select fused in.
__global__ __launch_bounds__(256, 4) void k_topk(
        const float* __restrict__ dc, const float* __restrict__ x,
        uint32_t* __restrict__ hist4, uint32_t* __restrict__ tiecnt,
        unsigned long long* __restrict__ gt, uint32_t* __restrict__ ties,
        uint32_t* __restrict__ cnt, float* __restrict__ mapA3, float* __restrict__ Ap3) {
    int b = blockIdx.x / BLKPB;
    int blk = blockIdx.x % BLKPB;
    int t = threadIdx.x;
    __shared__ uint32_t h[256];
    __shared__ uint2 bc;
    __shared__ uint32_t tl[CAP];
    __shared__ unsigned long long red[256];

    uint32_t pref = 0, target = KSEL;
    const float4* d4 = (const float4*)(dc + (size_t)b * HW + blk * CHUNK);

    for (int p = 0; p < 4; ++p) {
        int shift = 24 - 8 * p;
        uint32_t maskhi = (p == 0) ? 0u : (0xFFFFFFFFu << (shift + 8));
        h[t] = 0;
        __syncthreads();
        #pragma unroll
        for (int it = 0; it < CHUNK / 1024; ++it) {
            float4 v = d4[it * 256 + t];
            uint32_t u;
            u = __float_as_uint(v.x); if ((u & maskhi) == pref) atomicAdd(&h[(u >> shift) & 0xFFu], 1u);
            u = __float_as_uint(v.y); if ((u & maskhi) == pref) atomicAdd(&h[(u >> shift) & 0xFFu], 1u);
            u = __float_as_uint(v.z); if ((u & maskhi) == pref) atomicAdd(&h[(u >> shift) & 0xFFu], 1u);
            u = __float_as_uint(v.w); if ((u & maskhi) == pref) atomicAdd(&h[(u >> shift) & 0xFFu], 1u);
        }
        __syncthreads();
        uint32_t c = h[t];
        if (c) atomicAdd(&hist4[p * 4096 + b * 256 + t], c);
        // ---- grid barrier p ----
        __syncthreads();
        if (t == 0) {
            __threadfence();
            __hip_atomic_fetch_add(&cnt[p], 1u, __ATOMIC_RELEASE, __HIP_MEMORY_SCOPE_AGENT);
            while (__hip_atomic_load(&cnt[p], __ATOMIC_ACQUIRE, __HIP_MEMORY_SCOPE_AGENT) < (uint32_t)TOPK_BLOCKS)
                __builtin_amdgcn_s_sleep(2);
        }
        __syncthreads();
        // every block scans its batch's histogram locally (1 KB, L2-hot)
        h[t] = aload(&hist4[p * 4096 + b * 256 + t]);
        __syncthreads();
        if (t == 0) {
            uint32_t cum = 0, digit = 0, tgt = target;
            for (int i = 255; i >= 0; --i) {
                uint32_t c2 = h[i];
                if (cum + c2 >= tgt) { digit = (uint32_t)i; tgt -= cum; break; }
                cum += c2;
            }
            bc = make_uint2(digit, tgt);
        }
        __syncthreads();
        pref |= bc.x << shift;
        target = bc.y;
        __syncthreads();
    }

    // ---- collect over this block's chunk ----
    uint32_t v = pref;
    int rembase = blk * CHUNK;
    #pragma unroll
    for (int it = 0; it < CHUNK / 1024; ++it) {
        float4 vv = d4[it * 256 + t];
        int rem0 = rembase + (it * 256 + t) * 4;
        #pragma unroll
        for (int e = 0; e < 4; ++e) {
            float fv = (e == 0) ? vv.x : (e == 1) ? vv.y : (e == 2) ? vv.z : vv.w;
            uint32_t u = __float_as_uint(fv);
            if (u < v) continue;
            int rem = rem0 + e;
            if (u > v) {
                const float* xb = x + (size_t)b * 3 * HW + rem;
                float i0 = img01(xb[0]), i1 = img01(xb[HW]), i2 = img01(xb[2 * HW]);
                float inten = luma3(i0, i1, i2);
                unsigned long long packed =
                    ((unsigned long long)__float_as_uint(inten) << 32) | (uint32_t)(0xFFFFFFFFu - (uint32_t)rem);
                atomicMax(&gt[b], packed);
            } else {
                uint32_t pos = atomicAdd(&tiecnt[b], 1u);
                if (pos < CAP) ties[(size_t)b * CAP + pos] = (uint32_t)rem;
            }
        }
    }

    // ---- final barrier: non-select blocks arrive and exit ----
    __syncthreads();
    if (blk != 0) {
        if (t == 0) {
            __threadfence();
            __hip_atomic_fetch_add(&cnt[4], 1u, __ATOMIC_RELEASE, __HIP_MEMORY_SCOPE_AGENT);
        }
        return;
    }
    if (t == 0) {
        __threadfence();
        __hip_atomic_fetch_add(&cnt[4], 1u, __ATOMIC_RELEASE, __HIP_MEMORY_SCOPE_AGENT);
        while (__hip_atomic_load(&cnt[4], __ATOMIC_ACQUIRE, __HIP_MEMORY_SCOPE_AGENT) < (uint32_t)TOPK_BLOCKS)
            __builtin_amdgcn_s_sleep(2);
    }
    __syncthreads();

    // ---- select (one block per batch): rank ties by index, take r smallest, argmax intensity ----
    uint32_t n = aload(&tiecnt[b]);
    if (n > CAP) n = CAP;
    uint32_t r = target;
    for (uint32_t i = t; i < n; i += 256) tl[i] = aload(&ties[(size_t)b * CAP + i]);
    __syncthreads();
    unsigned long long best = 0;
    for (uint32_t i = t; i < n; i += 256) {
        uint32_t myidx = tl[i];
        uint32_t rank = 0;
        for (uint32_t j = 0; j < n; ++j) rank += (tl[j] < myidx) ? 1u : 0u;
        if (rank < r) {
            const float* xb = x + (size_t)b * 3 * HW + myidx;
            float i0 = img01(xb[0]), i1 = img01(xb[HW]), i2 = img01(xb[2 * HW]);
            float inten = luma3(i0, i1, i2);
            unsigned long long packed =
                ((unsigned long long)__float_as_uint(inten) << 32) | (uint32_t)(0xFFFFFFFFu - myidx);
            if (packed > best) best = packed;
        }
    }
    red[t] = best;
    __syncthreads();
    for (int s2 = 128; s2 > 0; s2 >>= 1) {
        if (t < s2) red[t] = (red[t] > red[t + s2]) ? red[t] : red[t + s2];
        __syncthreads();
    }
    if (t == 0) {
        unsigned long long tie = red[0], g = aload64(&gt[b]);
        unsigned long long fin = ((g >> 32) >= (tie >> 32)) ? g : tie;
        if (g == 0ull) fin = tie;
        uint32_t rem = 0xFFFFFFFFu - (uint32_t)(fin & 0xFFFFFFFFull);
        const float* xb = x + (size_t)b * 3 * HW + rem;
        for (int c = 0; c < 3; ++c) {
            float A = img01(xb[c * HW]);
            float mA = __fsub_rn(__fmul_rn(A, 2.0f), 1.0f);
            float Ap = __fmul_rn(__fadd_rn(mA, 1.0f), 0.5f);
            mapA3[b * 3 + c] = mA;
            Ap3[b * 3 + c] = Ap;
        }
    }
}

// ============ fused: col-min(15) of rm -> trans_raw -> GF row sums {I,p,Ip,II} ============
__global__ void k_trans_row1(const float* __restrict__ rm, const float* __restrict__ Ib,
                             float* __restrict__ rs) {
    int bid = blockIdx.x;              // 16*32
    int b = bid >> 5, seg = bid & 31;
    int y0 = seg * 16;
    int col = threadIdx.x;             // 512 threads, one per column
    __shared__ float LI[544], LP[544]; // logical [-16,527], offset 16, pad 0
    const float* rmp = rm + (size_t)b * HW;
    float rv[30];
    #pragma unroll
    for (int rix = 0; rix < 30; ++rix) {
        int gy = y0 - 7 + rix;
        rv[rix] = (gy >= 0 && gy < 512) ? rmp[(size_t)gy * WW + col] : 1e30f;
    }
    float pv[16];
    #pragma unroll
    for (int j = 0; j < 16; ++j) {
        float m = rv[j];
        #pragma unroll
        for (int k = 1; k < 15; ++k) m = fminf(m, rv[j + k]);
        int y = y0 + j;
        if (y < 7 || y > 504) m = fminf(m, 1.0f);   // window clipped -> pad 1.0 participates
        pv[j] = __fsub_rn(1.0f, __fmul_rn(0.95f, m));
    }
    if (col < 32) {
        int i = (col < 16) ? col : (512 + col);
        LI[i] = 0.f; LP[i] = 0.f;
    }
    const float* ibp = Ib + (size_t)b * HW;
    #pragma unroll
    for (int j = 0; j < 16; ++j) {
        int y = y0 + j;
        LI[16 + col] = ibp[(size_t)y * WW + col];
        LP[16 + col] = pv[j];
        __syncthreads();
        float sI = 0.f, sP = 0.f, sIP = 0.f, sII = 0.f;
        #pragma unroll
        for (int k = -15; k <= 15; ++k) {
            float iv = LI[16 + col + k], pp = LP[16 + col + k];
            sI += iv; sP += pp; sIP += iv * pp; sII += iv * iv;
        }
        size_t o = (size_t)b * HW + (size_t)y * WW + col;
        rs[o] = sI;
        rs[(size_t)BHW + o] = sP;
        rs[(size_t)2 * BHW + o] = sIP;
        rs[(size_t)3 * BHW + o] = sII;
        __syncthreads();
    }
}

// ============ fused: GF col running-sums -> a,b (LDS) -> row sums ra,rb ============
__global__ void k_colab_row2(const float* __restrict__ rs, float* __restrict__ ra,
                             float* __restrict__ rb) {
    int bid = blockIdx.x;              // 16*32
    int b = bid >> 5, seg = bid & 31;
    int y0 = seg * 16;
    int col = threadIdx.x;             // 512 threads
    __shared__ float La[544], Lb[544];
    const float* rI = rs;
    const float* rP = rs + (size_t)BHW;
    const float* rIP = rs + (size_t)2 * BHW;
    const float* rII = rs + (size_t)3 * BHW;
    size_t pc = (size_t)b * HW + col;
    float sI = 0.f, sP = 0.f, sIP = 0.f, sII = 0.f;
    for (int yy = y0 - 15; yy <= y0 + 15; ++yy) {
        if (yy >= 0 && yy < 512) {
            size_t o = pc + (size_t)yy * WW;
            sI += rI[o]; sP += rP[o]; sIP += rIP[o]; sII += rII[o];
        }
    }
    int nx = min(511, col + 15) - max(0, col - 15) + 1;
    if (col < 32) {
        int i = (col < 16) ? col : (512 + col);
        La[i] = 0.f; Lb[i] = 0.f;
    }
    for (int j = 0; j < 16; ++j) {
        int y = y0 + j;
        if (j > 0) {
            int ya = y + 15, yr = y - 16;
            if (ya < 512) {
                size_t o = pc + (size_t)ya * WW;
                sI += rI[o]; sP += rP[o]; sIP += rIP[o]; sII += rII[o];
            }
            if (yr >= 0) {
                size_t o = pc + (size_t)yr * WW;
                sI -= rI[o]; sP -= rP[o]; sIP -= rIP[o]; sII -= rII[o];
            }
        }
        int ny = min(511, y + 15) - max(0, y - 15) + 1;
        float N = (float)(ny * nx);
        float mI = sI / N, mP = sP / N, mIP = sIP / N, mII = sII / N;
        float cov = mIP - mI * mP;
        float var = mII - mI * mI;
        float a = cov / (var + 1e-3f);
        float bb = mP - a * mI;
        La[16 + col] = a;
        Lb[16 + col] = bb;
        __syncthreads();
        float sa = 0.f, sb = 0.f;
        #pragma unroll
        for (int k = -15; k <= 15; ++k) {
            sa += La[16 + col + k];
            sb += Lb[16 + col + k];
        }
        size_t o = pc + (size_t)y * WW;
        ra[o] = sa;
        rb[o] = sb;
        __syncthreads();
    }
}

// ============ final: running column sums of ra,rb -> T, J, mapA (16-row segments) ============
__global__ void k_final_col(const float* __restrict__ ra, const float* __restrict__ rb,
                            const float* __restrict__ Ib, const float* __restrict__ x,
                            const float* __restrict__ mapA3, float* __restrict__ out) {
    int bid = blockIdx.x;
    int b = bid >> 6, cg = (bid >> 5) & 1, seg = bid & 31;
    int col = cg * 256 + threadIdx.x;
    int y0 = seg * 16;
    size_t pc = (size_t)b * HW + col;
    float mA0 = mapA3[b * 3 + 0], mA1 = mapA3[b * 3 + 1], mA2 = mapA3[b * 3 + 2];
    const float* x0p = x + (size_t)b * 3 * HW + col;
    float Sa = 0.f, Sb = 0.f;
    for (int yy = y0 - 15; yy <= y0 + 15; ++yy) {
        if (yy >= 0 && yy < 512) {
            size_t o = pc + (size_t)yy * WW;
            Sa += ra[o]; Sb += rb[o];
        }
    }
    int nx = min(511, col + 15) - max(0, col - 15) + 1;
    for (int j = 0; j < 16; ++j) {
        int y = y0 + j;
        if (j > 0) {
            int ya = y + 15, yr = y - 16;
            if (ya < 512) {
                size_t o = pc + (size_t)ya * WW;
                Sa += ra[o]; Sb += rb[o];
            }
            if (yr >= 0) {
                size_t o = pc + (size_t)yr * WW;
                Sa -= ra[o]; Sb -= rb[o];
            }
        }
        int ny = min(511, y + 15) - max(0, y - 15) + 1;
        float N = (float)(ny * nx);
        float ma = Sa / N, mb = Sb / N;
        size_t yo = (size_t)y * WW;
        float Iv = Ib[pc + yo];
        float T = ma * Iv + mb;
        out[(size_t)3 * BHW + pc + yo] = T;
        float i0 = img01(x0p[yo]);
        float i1 = img01(x0p[(size_t)HW + yo]);
        float i2 = img01(x0p[(size_t)2 * HW + yo]);
        size_t j0 = (size_t)(b * 3) * HW + yo + col;
        out[j0] = (i0 - mA0) / T + mA0;
        out[j0 + HW] = (i1 - mA1) / T + mA1;
        out[j0 + 2 * HW] = (i2 - mA2) / T + mA2;
        out[(size_t)4 * BHW + j0] = mA0;
        out[(size_t)4 * BHW + j0 + HW] = mA1;
        out[(size_t)4 * BHW + j0 + 2 * HW] = mA2;
    }
}

extern "C" void kernel_launch(void* const* d_in, const int* in_sizes, int n_in,
                              void* d_out, int out_size, void* d_ws, size_t ws_size,
                              hipStream_t stream) {
    const float* x = (const float*)d_in[0];
    float* out = (float*)d_out;
    char* ws = (char*)d_ws;

    // ws planes
    float* Ib = (float*)ws;                    // guidance
    float* rm = Ib + (size_t)BHW;              // row-min tmp; later ra
    float* dc = Ib + (size_t)2 * BHW;          // dark channel; later rb
    char* small = ws + (size_t)3 * BHW * 4;
    uint32_t* hist4 = (uint32_t*)(small);                        // 4*16*256 u32 = 64 KB
    uint32_t* cnt = (uint32_t*)(small + 65536);                  // 8 barrier counters
    uint32_t* tiecnt = (uint32_t*)(small + 65600);
    unsigned long long* gt = (unsigned long long*)(small + 65664);
    float* mapA3 = (float*)(small + 65792);
    float* Ap3 = (float*)(small + 66048);
    uint32_t* ties = (uint32_t*)(small + 66304);                 // 16*CAP u32 = 512 KB
    // d_out reuse: rs planes 0..3 (consumed by colab_row2 before final writes)
    float* rs = out;
    float* ra = rm;
    float* rb = dc;

    // dark channel of imgPatch (bit-exact min path) + topk-state init
    k_dc_row<<<16 * 512, 256, 0, stream>>>(x, Ib, rm, hist4, tiecnt, gt, cnt);
    k_dc_col0<<<16 * 4 * 8, 256, 0, stream>>>(rm, dc);

    // exact top-k + atmospheric light, single cooperative kernel
    {
        void* args[] = {(void*)&dc, (void*)&x, (void*)&hist4, (void*)&tiecnt,
                        (void*)&gt, (void*)&ties, (void*)&cnt, (void*)&mapA3, (void*)&Ap3};
        hipLaunchCooperativeKernel((const void*)k_topk, dim3(TOPK_BLOCKS), dim3(256),
                                   args, 0, stream);
    }

    // trans_raw = 1 - 0.95 * darkchannel(imgPatch / A), fused with GF row pass 1
    k_dc2_row<<<16 * 512, 256, 0, stream>>>(x, Ap3, rm);
    k_trans_row1<<<16 * 32, 512, 0, stream>>>(rm, Ib, rs);

    // GF col pass + a,b + row sums (fused), then final col pass + outputs
    k_colab_row2<<<16 * 32, 512, 0, stream>>>(rs, ra, rb);
    k_final_col<<<16 * 2 * 32, 256, 0, stream>>>(ra, rb, Ib, x, mapA3, out);
}

// Round 6
// 272.915 us; speedup vs baseline: 2.9781x; 2.9781x over previous
//
#include <hip/hip_runtime.h>
#include <stdint.h>

#define BB 16
#define HH 512
#define WW 512
#define HW 262144            // 2^18
#define BHW 4194304          // 16 * 2^18
#define KSEL 262
#define CAP 8192
#define NCAND (64 * 262)     // candidates per batch after phase A

// ---------- helpers (rn intrinsics to suppress fma contraction in selection-critical math) ----------
__device__ __forceinline__ float img01(float xv) {
    return __fmul_rn(__fadd_rn(xv, 1.0f), 0.5f);
}
__device__ __forceinline__ float luma3(float c0, float c1, float c2) {
    float t = __fadd_rn(__fmul_rn(0.2989f, c0), __fmul_rn(0.587f, c1));
    return __fadd_rn(t, __fmul_rn(0.114f, c2));
}

// ============ dark channel row pass (fused prep): x -> Ib (guidance), rm (row min of cmin) ============
__global__ void k_dc_row(const float* __restrict__ x, float* __restrict__ Ib, float* __restrict__ rm) {
    int bid = blockIdx.x;              // 16*512
    int b = bid >> 9, y = bid & 511;
    int t = threadIdx.x;
    __shared__ float lcm[528];         // logical [-8, 519], offset 8, pad = 1.0
    const float* xb = x + (size_t)b * 3 * HW + (size_t)y * WW;
    size_t obase = (size_t)b * HW + (size_t)y * WW;
    for (int xx = t; xx < 512; xx += 256) {
        float x0 = xb[xx], x1 = xb[HW + xx], x2 = xb[2 * HW + xx];
        float i0 = img01(x0), i1 = img01(x1), i2 = img01(x2);
        lcm[8 + xx] = fminf(i0, fminf(i1, i2));
        float tt = luma3(x0, x1, x2);
        Ib[obase + xx] = __fmul_rn(__fadd_rn(tt, 1.0f), 0.5f);
    }
    if (t < 16) lcm[(t < 8) ? t : (512 + t)] = 1.0f;
    __syncthreads();
    for (int xx = t; xx < 512; xx += 256) {
        float m = lcm[8 + xx - 7];
        #pragma unroll
        for (int k = -6; k <= 7; ++k) m = fminf(m, lcm[8 + xx + k]);
        rm[obase + xx] = m;
    }
}

// ============ second dark channel row pass (fused cmin2): x, Ap3 -> rm ============
__global__ void k_dc2_row(const float* __restrict__ x, const float* __restrict__ Ap3,
                          float* __restrict__ rm) {
    int bid = blockIdx.x;
    int b = bid >> 9, y = bid & 511;
    int t = threadIdx.x;
    __shared__ float lcm[528];
    const float* xb = x + (size_t)b * 3 * HW + (size_t)y * WW;
    float a0 = Ap3[b * 3 + 0], a1 = Ap3[b * 3 + 1], a2 = Ap3[b * 3 + 2];
    size_t obase = (size_t)b * HW + (size_t)y * WW;
    for (int xx = t; xx < 512; xx += 256) {
        float v0 = __fdiv_rn(img01(xb[xx]), a0);
        float v1 = __fdiv_rn(img01(xb[HW + xx]), a1);
        float v2 = __fdiv_rn(img01(xb[2 * HW + xx]), a2);
        lcm[8 + xx] = fminf(v0, fminf(v1, v2));
    }
    if (t < 16) lcm[(t < 8) ? t : (512 + t)] = 1.0f;
    __syncthreads();
    for (int xx = t; xx < 512; xx += 256) {
        float m = lcm[8 + xx - 7];
        #pragma unroll
        for (int k = -6; k <= 7; ++k) m = fminf(m, lcm[8 + xx + k]);
        rm[obase + xx] = m;
    }
}

// ============ col min pass (dark channel only): rm -> dc ============
__global__ void k_dc_col0(const float* __restrict__ in, float* __restrict__ out) {
    // grid 16*4*8; tile 128 cols x (64+14) rows
    int bid = blockIdx.x;
    int b = bid >> 5, cg = (bid >> 3) & 3, seg = bid & 7;
    int c0 = cg * 128, y0 = seg * 64;
    int t = threadIdx.x;
    __shared__ float tile[78 * 128];
    const float* ib = in + (size_t)b * HW;
    for (int i = t; i < 78 * 128; i += 256) {
        int rr = i >> 7, cc = i & 127;
        int gy = y0 - 7 + rr;
        tile[i] = (gy >= 0 && gy < 512) ? ib[(size_t)gy * WW + c0 + cc] : 1.0f;
    }
    __syncthreads();
    int col = t & 127;
    int rbase = (t >> 7) * 32;
    size_t obase = (size_t)b * HW + c0 + col;
    for (int rr = rbase; rr < rbase + 32; ++rr) {
        float m = tile[rr * 128 + col];
        #pragma unroll
        for (int k = 1; k < 15; ++k) m = fminf(m, tile[(rr + k) * 128 + col]);
        out[obase + (size_t)(y0 + rr) * WW] = m;
    }
}

// ============ phase A: per-block exact local top-262, all in LDS (no inter-block comm) ============
// Each block: stage 4096-elem chunk; 4x8-bit radix select (LDS hist + suffix scan);
// ordered compaction emits exactly 262 (value desc, index asc) candidates.
__global__ __launch_bounds__(256) void k_topkA(const float* __restrict__ dc, uint2* __restrict__ cand) {
    int b = blockIdx.x >> 6, blk = blockIdx.x & 63;
    int t = threadIdx.x;
    __shared__ uint32_t sv[4096];
    __shared__ uint32_t h[1024];       // 4 sub-histograms (wave-split to cut same-bin serialization)
    __shared__ uint32_t sc[256];
    __shared__ uint32_t sdigit, stgt;
    const uint4* d4 = (const uint4*)(dc + (size_t)b * HW + blk * 4096);
    #pragma unroll
    for (int it = 0; it < 4; ++it) {
        uint4 v = d4[it * 256 + t];
        int o = (it * 256 + t) * 4;
        sv[o] = v.x; sv[o + 1] = v.y; sv[o + 2] = v.z; sv[o + 3] = v.w;
    }
    __syncthreads();
    uint32_t pref = 0, target = KSEL;
    int hb = ((t >> 6) & 3) * 256;
    for (int p = 0; p < 4; ++p) {
        int shift = 24 - 8 * p;
        uint32_t maskhi = p ? (0xFFFFFFFFu << (shift + 8)) : 0u;
        h[t] = 0; h[256 + t] = 0; h[512 + t] = 0; h[768 + t] = 0;
        __syncthreads();
        #pragma unroll
        for (int e = 0; e < 16; ++e) {
            uint32_t u = sv[t * 16 + e];
            if ((u & maskhi) == pref) atomicAdd(&h[hb + ((u >> shift) & 0xFFu)], 1u);
        }
        __syncthreads();
        sc[t] = h[t] + h[256 + t] + h[512 + t] + h[768 + t];
        __syncthreads();
        // inclusive suffix sum: sc[t] = sum_{j>=t}
        for (int off = 1; off < 256; off <<= 1) {
            uint32_t add = (t + off < 256) ? sc[t + off] : 0u;
            __syncthreads();
            sc[t] += add;
            __syncthreads();
        }
        uint32_t St = sc[t], St1 = (t < 255) ? sc[t + 1] : 0u;
        if (St >= target && St1 < target) { sdigit = (uint32_t)t; stgt = target - St1; }
        __syncthreads();
        pref |= sdigit << shift;
        target = stgt;
        __syncthreads();
    }
    // ordered compaction: all u > pref (G of them), plus first `target` ties in index order
    uint32_t cg = 0, ct = 0;
    #pragma unroll
    for (int e = 0; e < 16; ++e) {
        uint32_t u = sv[t * 16 + e];
        cg += (u > pref) ? 1u : 0u;
        ct += (u == pref) ? 1u : 0u;
    }
    uint32_t packed = (cg << 16) | ct;   // counts <= 4096, fit 16 bits each
    sc[t] = packed;
    __syncthreads();
    for (int off = 1; off < 256; off <<= 1) {
        uint32_t add = (t >= off) ? sc[t - off] : 0u;
        __syncthreads();
        sc[t] += add;
        __syncthreads();
    }
    uint32_t excl = sc[t] - packed;
    uint32_t G = sc[255] >> 16;
    uint32_t gpos = excl >> 16, tpos = excl & 0xFFFFu;
    uint2* cb = cand + (size_t)(b * 64 + blk) * 262;
    #pragma unroll
    for (int e = 0; e < 16; ++e) {
        uint32_t u = sv[t * 16 + e];
        uint32_t idx = (uint32_t)(blk * 4096 + t * 16 + e);
        if (u > pref) { cb[gpos] = make_uint2(u, idx); ++gpos; }
        else if (u == pref) { if (tpos < target) cb[G + tpos] = make_uint2(u, idx); ++tpos; }
    }
}

// ============ phase B: merge 64*262 candidates per batch -> exact v,r -> A selection ============
__global__ __launch_bounds__(256) void k_topkB(const uint2* __restrict__ cand, const float* __restrict__ x,
                                               float* __restrict__ mapA3, float* __restrict__ Ap3) {
    int b = blockIdx.x, t = threadIdx.x;
    __shared__ uint32_t h[1024];
    __shared__ uint32_t sc[256];
    __shared__ uint32_t sdigit, stgt, ntie;
    __shared__ uint32_t tl[CAP];
    __shared__ unsigned long long red[256];
    const uint2* cb = cand + (size_t)b * NCAND;
    uint32_t pref = 0, target = KSEL;
    int hb = ((t >> 6) & 3) * 256;
    for (int p = 0; p < 4; ++p) {
        int shift = 24 - 8 * p;
        uint32_t maskhi = p ? (0xFFFFFFFFu << (shift + 8)) : 0u;
        h[t] = 0; h[256 + t] = 0; h[512 + t] = 0; h[768 + t] = 0;
        __syncthreads();
        for (int i = t; i < NCAND; i += 256) {
            uint32_t u = cb[i].x;
            if ((u & maskhi) == pref) atomicAdd(&h[hb + ((u >> shift) & 0xFFu)], 1u);
        }
        __syncthreads();
        sc[t] = h[t] + h[256 + t] + h[512 + t] + h[768 + t];
        __syncthreads();
        for (int off = 1; off < 256; off <<= 1) {
            uint32_t add = (t + off < 256) ? sc[t + off] : 0u;
            __syncthreads();
            sc[t] += add;
            __syncthreads();
        }
        uint32_t St = sc[t], St1 = (t < 255) ? sc[t + 1] : 0u;
        if (St >= target && St1 < target) { sdigit = (uint32_t)t; stgt = target - St1; }
        __syncthreads();
        pref |= sdigit << shift;
        target = stgt;
        __syncthreads();
    }
    // collect: strict-greater best (per-thread + reduce), ties into tl
    if (t == 0) ntie = 0;
    __syncthreads();
    unsigned long long bg = 0;
    for (int i = t; i < NCAND; i += 256) {
        uint2 cv = cb[i];
        uint32_t u = cv.x;
        if (u < pref) continue;
        if (u > pref) {
            const float* xb = x + (size_t)b * 3 * HW + cv.y;
            float i0 = img01(xb[0]), i1 = img01(xb[HW]), i2 = img01(xb[2 * HW]);
            float inten = luma3(i0, i1, i2);
            unsigned long long pk =
                ((unsigned long long)__float_as_uint(inten) << 32) | (uint32_t)(0xFFFFFFFFu - cv.y);
            if (pk > bg) bg = pk;
        } else {
            uint32_t pos = atomicAdd(&ntie, 1u);
            if (pos < CAP) tl[pos] = cv.y;
        }
    }
    __syncthreads();
    uint32_t n = ntie; if (n > CAP) n = CAP;
    uint32_t r = target;
    unsigned long long bt = 0;
    for (uint32_t i = t; i < n; i += 256) {
        uint32_t myidx = tl[i];
        uint32_t rank = 0;
        for (uint32_t j = 0; j < n; ++j) rank += (tl[j] < myidx) ? 1u : 0u;
        if (rank < r) {
            const float* xb = x + (size_t)b * 3 * HW + myidx;
            float i0 = img01(xb[0]), i1 = img01(xb[HW]), i2 = img01(xb[2 * HW]);
            float inten = luma3(i0, i1, i2);
            unsigned long long pk =
                ((unsigned long long)__float_as_uint(inten) << 32) | (uint32_t)(0xFFFFFFFFu - myidx);
            if (pk > bt) bt = pk;
        }
    }
    red[t] = bg;
    __syncthreads();
    for (int s2 = 128; s2 > 0; s2 >>= 1) {
        if (t < s2) red[t] = (red[t] > red[t + s2]) ? red[t] : red[t + s2];
        __syncthreads();
    }
    unsigned long long g = red[0];
    __syncthreads();
    red[t] = bt;
    __syncthreads();
    for (int s2 = 128; s2 > 0; s2 >>= 1) {
        if (t < s2) red[t] = (red[t] > red[t + s2]) ? red[t] : red[t + s2];
        __syncthreads();
    }
    if (t == 0) {
        unsigned long long tie = red[0];
        unsigned long long fin = ((g >> 32) >= (tie >> 32)) ? g : tie;   // equal intensity -> gt wins
        if (g == 0ull) fin = tie;
        uint32_t rem = 0xFFFFFFFFu - (uint32_t)(fin & 0xFFFFFFFFull);
        const float* xb = x + (size_t)b * 3 * HW + rem;
        for (int c = 0; c < 3; ++c) {
            float A = img01(xb[c * HW]);
            float mA = __fsub_rn(__fmul_rn(A, 2.0f), 1.0f);
            float Ap = __fmul_rn(__fadd_rn(mA, 1.0f), 0.5f);
            mapA3[b * 3 + c] = mA;
            Ap3[b * 3 + c] = Ap;
        }
    }
}

// ============ fused: col-min(15) of rm -> trans_raw -> GF row sums {I,p,Ip,II} ============
__global__ void k_trans_row1(const float* __restrict__ rm, const float* __restrict__ Ib,
                             float* __restrict__ rs) {
    int bid = blockIdx.x;              // 16*32
    int b = bid >> 5, seg = bid & 31;
    int y0 = seg * 16;
    int col = threadIdx.x;             // 512 threads, one per column
    __shared__ float LI[544], LP[544]; // logical [-16,527], offset 16, pad 0
    const float* rmp = rm + (size_t)b * HW;
    float rv[30];
    #pragma unroll
    for (int rix = 0; rix < 30; ++rix) {
        int gy = y0 - 7 + rix;
        rv[rix] = (gy >= 0 && gy < 512) ? rmp[(size_t)gy * WW + col] : 1e30f;
    }
    float pv[16];
    #pragma unroll
    for (int j = 0; j < 16; ++j) {
        float m = rv[j];
        #pragma unroll
        for (int k = 1; k < 15; ++k) m = fminf(m, rv[j + k]);
        int y = y0 + j;
        if (y < 7 || y > 504) m = fminf(m, 1.0f);   // window clipped -> pad 1.0 participates
        pv[j] = __fsub_rn(1.0f, __fmul_rn(0.95f, m));
    }
    if (col < 32) {
        int i = (col < 16) ? col : (512 + col);
        LI[i] = 0.f; LP[i] = 0.f;
    }
    const float* ibp = Ib + (size_t)b * HW;
    #pragma unroll
    for (int j = 0; j < 16; ++j) {
        int y = y0 + j;
        LI[16 + col] = ibp[(size_t)y * WW + col];
        LP[16 + col] = pv[j];
        __syncthreads();
        float sI = 0.f, sP = 0.f, sIP = 0.f, sII = 0.f;
        #pragma unroll
        for (int k = -15; k <= 15; ++k) {
            float iv = LI[16 + col + k], pp = LP[16 + col + k];
            sI += iv; sP += pp; sIP += iv * pp; sII += iv * iv;
        }
        size_t o = (size_t)b * HW + (size_t)y * WW + col;
        rs[o] = sI;
        rs[(size_t)BHW + o] = sP;
        rs[(size_t)2 * BHW + o] = sIP;
        rs[(size_t)3 * BHW + o] = sII;
        __syncthreads();
    }
}

// ============ fused: GF col running-sums -> a,b (LDS) -> row sums ra,rb ============
__global__ void k_colab_row2(const float* __restrict__ rs, float* __restrict__ ra,
                             float* __restrict__ rb) {
    int bid = blockIdx.x;              // 16*32
    int b = bid >> 5, seg = bid & 31;
    int y0 = seg * 16;
    int col = threadIdx.x;             // 512 threads
    __shared__ float La[544], Lb[544];
    const float* rI = rs;
    const float* rP = rs + (size_t)BHW;
    const float* rIP = rs + (size_t)2 * BHW;
    const float* rII = rs + (size_t)3 * BHW;
    size_t pc = (size_t)b * HW + col;
    float sI = 0.f, sP = 0.f, sIP = 0.f, sII = 0.f;
    for (int yy = y0 - 15; yy <= y0 + 15; ++yy) {
        if (yy >= 0 && yy < 512) {
            size_t o = pc + (size_t)yy * WW;
            sI += rI[o]; sP += rP[o]; sIP += rIP[o]; sII += rII[o];
        }
    }
    int nx = min(511, col + 15) - max(0, col - 15) + 1;
    if (col < 32) {
        int i = (col < 16) ? col : (512 + col);
        La[i] = 0.f; Lb[i] = 0.f;
    }
    for (int j = 0; j < 16; ++j) {
        int y = y0 + j;
        if (j > 0) {
            int ya = y + 15, yr = y - 16;
            if (ya < 512) {
                size_t o = pc + (size_t)ya * WW;
                sI += rI[o]; sP += rP[o]; sIP += rIP[o]; sII += rII[o];
            }
            if (yr >= 0) {
                size_t o = pc + (size_t)yr * WW;
                sI -= rI[o]; sP -= rP[o]; sIP -= rIP[o]; sII -= rII[o];
            }
        }
        int ny = min(511, y + 15) - max(0, y - 15) + 1;
        float N = (float)(ny * nx);
        float mI = sI / N, mP = sP / N, mIP = sIP / N, mII = sII / N;
        float cov = mIP - mI * mP;
        float var = mII - mI * mI;
        float a = cov / (var + 1e-3f);
        float bb = mP - a * mI;
        La[16 + col] = a;
        Lb[16 + col] = bb;
        __syncthreads();
        float sa = 0.f, sb = 0.f;
        #pragma unroll
        for (int k = -15; k <= 15; ++k) {
            sa += La[16 + col + k];
            sb += Lb[16 + col + k];
        }
        size_t o = pc + (size_t)y * WW;
        ra[o] = sa;
        rb[o] = sb;
        __syncthreads();
    }
}

// ============ final: running column sums of ra,rb -> T, J, mapA (16-row segments) ============
__global__ void k_final_col(const float* __restrict__ ra, const float* __restrict__ rb,
                            const float* __restrict__ Ib, const float* __restrict__ x,
                            const float* __restrict__ mapA3, float* __restrict__ out) {
    int bid = blockIdx.x;
    int b = bid >> 6, cg = (bid >> 5) & 1, seg = bid & 31;
    int col = cg * 256 + threadIdx.x;
    int y0 = seg * 16;
    size_t pc = (size_t)b * HW + col;
    float mA0 = mapA3[b * 3 + 0], mA1 = mapA3[b * 3 + 1], mA2 = mapA3[b * 3 + 2];
    const float* x0p = x + (size_t)b * 3 * HW + col;
    float Sa = 0.f, Sb = 0.f;
    for (int yy = y0 - 15; yy <= y0 + 15; ++yy) {
        if (yy >= 0 && yy < 512) {
            size_t o = pc + (size_t)yy * WW;
            Sa += ra[o]; Sb += rb[o];
        }
    }
    int nx = min(511, col + 15) - max(0, col - 15) + 1;
    for (int j = 0; j < 16; ++j) {
        int y = y0 + j;
        if (j > 0) {
            int ya = y + 15, yr = y - 16;
            if (ya < 512) {
                size_t o = pc + (size_t)ya * WW;
                Sa += ra[o]; Sb += rb[o];
            }
            if (yr >= 0) {
                size_t o = pc + (size_t)yr * WW;
                Sa -= ra[o]; Sb -= rb[o];
            }
        }
        int ny = min(511, y + 15) - max(0, y - 15) + 1;
        float N = (float)(ny * nx);
        float ma = Sa / N, mb = Sb / N;
        size_t yo = (size_t)y * WW;
        float Iv = Ib[pc + yo];
        float T = ma * Iv + mb;
        out[(size_t)3 * BHW + pc + yo] = T;
        float i0 = img01(x0p[yo]);
        float i1 = img01(x0p[(size_t)HW + yo]);
        float i2 = img01(x0p[(size_t)2 * HW + yo]);
        size_t j0 = (size_t)(b * 3) * HW + yo + col;
        out[j0] = (i0 - mA0) / T + mA0;
        out[j0 + HW] = (i1 - mA1) / T + mA1;
        out[j0 + 2 * HW] = (i2 - mA2) / T + mA2;
        out[(size_t)4 * BHW + j0] = mA0;
        out[(size_t)4 * BHW + j0 + HW] = mA1;
        out[(size_t)4 * BHW + j0 + 2 * HW] = mA2;
    }
}

extern "C" void kernel_launch(void* const* d_in, const int* in_sizes, int n_in,
                              void* d_out, int out_size, void* d_ws, size_t ws_size,
                              hipStream_t stream) {
    const float* x = (const float*)d_in[0];
    float* out = (float*)d_out;
    char* ws = (char*)d_ws;

    // ws planes
    float* Ib = (float*)ws;                    // guidance
    float* rm = Ib + (size_t)BHW;              // row-min tmp; later ra
    float* dc = Ib + (size_t)2 * BHW;          // dark channel; later rb
    uint2* cand = (uint2*)(ws + (size_t)3 * BHW * 4);            // 16*64*262 uint2 = 2.1 MB
    char* small = ws + (size_t)3 * BHW * 4 + (size_t)4 * 1024 * 1024;
    float* mapA3 = (float*)(small);
    float* Ap3 = (float*)(small + 256);
    // d_out reuse: rs planes 0..3 (consumed by colab_row2 before final writes)
    float* rs = out;
    float* ra = rm;
    float* rb = dc;

    // dark channel of imgPatch (bit-exact min path)
    k_dc_row<<<16 * 512, 256, 0, stream>>>(x, Ib, rm);
    k_dc_col0<<<16 * 4 * 8, 256, 0, stream>>>(rm, dc);

    // exact top-k + atmospheric light: local top-262 per block, then merge (no grid sync)
    k_topkA<<<16 * 64, 256, 0, stream>>>(dc, cand);
    k_topkB<<<16, 256, 0, stream>>>(cand, x, mapA3, Ap3);

    // trans_raw = 1 - 0.95 * darkchannel(imgPatch / A), fused with GF row pass 1
    k_dc2_row<<<16 * 512, 256, 0, stream>>>(x, Ap3, rm);
    k_trans_row1<<<16 * 32, 512, 0, stream>>>(rm, Ib, rs);

    // GF col pass + a,b + row sums (fused), then final col pass + outputs
    k_colab_row2<<<16 * 32, 512, 0, stream>>>(rs, ra, rb);
    k_final_col<<<16 * 2 * 32, 256, 0, stream>>>(ra, rb, Ib, x, mapA3, out);
}